// Round 5
// baseline (1249.978 us; speedup 1.0000x reference)
//
#include <hip/hip_runtime.h>
#include <hip/hip_bf16.h>
#include <math.h>

#define N_ATOMS 524288
#define DIM 256
#define NB 16384          // number of molecules / segments
#define M_STEPS 6

#define SEG 64            // segments per block
#define NTHREADS 1024     // 16 waves -> 4 waves/SIMD (2x round-4 occupancy)
#define SEGW 4            // segments per wave
#define AST 520           // A row stride (fp16): 512 cols + 8 pad

typedef _Float16 f16x8 __attribute__((ext_vector_type(8)));
typedef float f32x16 __attribute__((ext_vector_type(16)));

__device__ __forceinline__ float sigmoidf_(float z) {
    return 1.0f / (1.0f + __expf(-z));
}
__device__ __forceinline__ float tanh_fast(float z) {
    return 1.0f - 2.0f / (__expf(2.0f * z) + 1.0f);
}
// unpack a uint holding two fp16
__device__ __forceinline__ float2 h2f2(unsigned u) {
    union { unsigned u; _Float16 h[2]; } x; x.u = u;
    float2 r; r.x = (float)x.h[0]; r.y = (float)x.h[1]; return r;
}

// ---------------------------------------------------------------------------
// Kernel 1: segment bounds via binary search (atom_split is sorted)
// ---------------------------------------------------------------------------
__global__ void bounds_kernel(const int* __restrict__ split, int* __restrict__ lb) {
    int b = blockIdx.x * blockDim.x + threadIdx.x;
    if (b > NB) return;
    int lo = 0, hi = N_ATOMS;
    while (lo < hi) {
        int mid = (lo + hi) >> 1;
        if (split[mid] < b) lo = mid + 1; else hi = mid;
    }
    lb[b] = lo;
}

// ---------------------------------------------------------------------------
// Kernel 2: pre-swizzle U (f32 [512,1024]) into fp16 B-fragment order for
// mfma_f32_32x32x16_f16. Frag f = nt*32 + kc; lane l holds
// B[k = kc*16 + (l>>5)*8 + jj][n = nt*32 + (l&31)], jj=0..7. 1 MB total.
// ---------------------------------------------------------------------------
__global__ __launch_bounds__(256) void uswz_kernel(const float* __restrict__ U,
                                                   _Float16* __restrict__ uh) {
    int d = blockIdx.x * 256 + threadIdx.x;
    int f = d >> 8;
    int r = d & 255;
    int jjp = r >> 6;
    int lane = r & 63;
    int nt = f >> 5, kc = f & 31;
    int n = nt * 32 + (lane & 31);
    int k = kc * 16 + (lane >> 5) * 8 + jjp * 2;
    union { unsigned u; _Float16 h[2]; } p;
    p.h[0] = (_Float16)U[(size_t)k * 1024 + n];
    p.h[1] = (_Float16)U[(size_t)(k + 1) * 1024 + n];
    *(unsigned*)(&uh[(size_t)(f * 64 + lane) * 8 + jjp * 2]) = p.u;
}

// ---------------------------------------------------------------------------
// Kernel 3: FULLY FUSED Set2Set, 16-wave blocks (4 waves/SIMD).
//   phase0: mean-attn over fp32 x (h=0 -> uniform softmax), emit fp16 x copy
//   5x { GEMM [h|r]@U via MFMA from LDS-A -> gates -> h,c ; attn over fp16 x }
// GEMM: wave = (mt = w>>3 row-tile, wn = w&7 col-tile), acc[4 gates][16].
// attn: 8 atoms/wave/iter (2 rows per 16-lane group) for 4 KB in-flight/wave.
// ---------------------------------------------------------------------------
__global__ __launch_bounds__(NTHREADS) void set2set_fused_kernel(
    const float* __restrict__ x,       // [N_ATOMS, DIM] fp32
    const int* __restrict__ lb,        // [NB+1]
    const _Float16* __restrict__ uh,   // pre-swizzled U fp16 fragments
    const float* __restrict__ bias,    // [1024]
    _Float16* __restrict__ xh,         // [N_ATOMS, DIM] fp16 scratch
    float* __restrict__ out)           // [NB, 512]
{
    extern __shared__ char smem[];
    _Float16 (*A)[AST]  = (_Float16(*)[AST])smem;                       // 66560 B
    float    (*Cs)[DIM] = (float(*)[DIM])(smem + SEG * AST * 2);        // 65536 B
    int*     lbs        = (int*)(smem + SEG * AST * 2 + SEG * DIM * 4); // 260 B

    const int t    = threadIdx.x;
    const int w    = t >> 6;
    const int lane = t & 63;
    const int g    = lane >> 4;       // atom subgroup 0..3
    const int q    = lane & 15;       // dim subgroup 0..15
    const int s0seg = blockIdx.x * SEG;

    if (t <= SEG) lbs[t] = lb[s0seg + t];
    // zero h-half of A and c
    for (int idx = t; idx < SEG * 64; idx += NTHREADS) {
        int row = idx >> 6, j4 = idx & 63;
        uint2 z; z.x = 0u; z.y = 0u;
        *(uint2*)(&A[row][j4 * 4]) = z;                 // cols 0..255 (h) = 0
        float4 zf = {0.f, 0.f, 0.f, 0.f};
        *(float4*)(&Cs[row][j4 * 4]) = zf;
    }
    // GEMM role of this wave: row-tile mt, col-tile wn; hoist bias
    const int mt    = w >> 3;
    const int wn    = w & 7;
    const int col32 = lane & 31;
    const int d     = wn * 32 + col32;
    const float bi  = bias[d];
    const float bf_ = bias[256 + d];
    const float bo  = bias[512 + d];
    const float bg  = bias[768 + d];
    __syncthreads();

#define XRED(v) { v += __shfl_xor(v, 16, 64); v += __shfl_xor(v, 32, 64); }

    // ---------------- phase 0: mean + fp16 conversion (4 atoms/iter) --------
    for (int js = 0; js < SEGW; ++js) {
        const int sl = w * SEGW + js;
        const int s = lbs[sl], e = lbs[sl + 1];
        float a0x=0.f,a0y=0.f,a0z=0.f,a0w=0.f;
        float a1x=0.f,a1y=0.f,a1z=0.f,a1w=0.f;
        float a2x=0.f,a2y=0.f,a2z=0.f,a2w=0.f;
        float a3x=0.f,a3y=0.f,a3z=0.f,a3w=0.f;
        float cnt = 0.f;
        int i = s + g;
        float4 c0={0,0,0,0}, c1={0,0,0,0}, c2={0,0,0,0}, c3={0,0,0,0};
        if (i < e) {
            const float* xr = &x[(size_t)i * DIM + q * 16];
            c0 = *(const float4*)(xr + 0);  c1 = *(const float4*)(xr + 4);
            c2 = *(const float4*)(xr + 8);  c3 = *(const float4*)(xr + 12);
        }
        while (i < e) {
            const int inext = i + 4;
            const int iload = (inext < e) ? inext : i;
            const float* xr = &x[(size_t)iload * DIM + q * 16];
            const float4 n0 = *(const float4*)(xr + 0);
            const float4 n1 = *(const float4*)(xr + 4);
            const float4 n2 = *(const float4*)(xr + 8);
            const float4 n3 = *(const float4*)(xr + 12);

            union { _Float16 h[16]; uint4 v[2]; } P;
            P.h[0]=(_Float16)c0.x; P.h[1]=(_Float16)c0.y; P.h[2]=(_Float16)c0.z; P.h[3]=(_Float16)c0.w;
            P.h[4]=(_Float16)c1.x; P.h[5]=(_Float16)c1.y; P.h[6]=(_Float16)c1.z; P.h[7]=(_Float16)c1.w;
            P.h[8]=(_Float16)c2.x; P.h[9]=(_Float16)c2.y; P.h[10]=(_Float16)c2.z; P.h[11]=(_Float16)c2.w;
            P.h[12]=(_Float16)c3.x; P.h[13]=(_Float16)c3.y; P.h[14]=(_Float16)c3.z; P.h[15]=(_Float16)c3.w;
            uint4* xw = (uint4*)(&xh[(size_t)i * DIM + q * 16]);
            xw[0] = P.v[0]; xw[1] = P.v[1];

            cnt += 1.f;
            a0x += c0.x; a0y += c0.y; a0z += c0.z; a0w += c0.w;
            a1x += c1.x; a1y += c1.y; a1z += c1.z; a1w += c1.w;
            a2x += c2.x; a2y += c2.y; a2z += c2.z; a2w += c2.w;
            a3x += c3.x; a3y += c3.y; a3z += c3.z; a3w += c3.w;
            c0=n0; c1=n1; c2=n2; c3=n3;
            i = inext;
        }
        XRED(a0x) XRED(a0y) XRED(a0z) XRED(a0w)
        XRED(a1x) XRED(a1y) XRED(a1z) XRED(a1w)
        XRED(a2x) XRED(a2y) XRED(a2z) XRED(a2w)
        XRED(a3x) XRED(a3y) XRED(a3z) XRED(a3w)
        XRED(cnt)
        const float inv = (cnt > 0.f) ? (1.0f / cnt) : 0.f;
        float vx = (g==0) ? a0x : (g==1) ? a1x : (g==2) ? a2x : a3x;
        float vy = (g==0) ? a0y : (g==1) ? a1y : (g==2) ? a2y : a3y;
        float vz = (g==0) ? a0z : (g==1) ? a1z : (g==2) ? a2z : a3z;
        float vw = (g==0) ? a0w : (g==1) ? a1w : (g==2) ? a2w : a3w;
        union { _Float16 h[4]; uint2 u; } R;
        R.h[0]=(_Float16)(vx*inv); R.h[1]=(_Float16)(vy*inv);
        R.h[2]=(_Float16)(vz*inv); R.h[3]=(_Float16)(vw*inv);
        *(uint2*)(&A[sl][256 + q * 16 + g * 4]) = R.u;
    }
    __syncthreads();

    // ---------------- 5 x (LSTM step + attention pass) ----------------
    for (int m = 0; m < M_STEPS - 1; ++m) {
        // ---- GEMM: z = [h|r] @ U.  A fp16 in LDS; wave does 32 rows x 32 cols x 4 gates.
        f32x16 acc[4];
        #pragma unroll
        for (int et = 0; et < 4; ++et)
            #pragma unroll
            for (int qq = 0; qq < 16; ++qq) acc[et][qq] = 0.0f;

        #pragma unroll 4
        for (int kc = 0; kc < 32; ++kc) {
            const int kof = kc * 16 + (lane >> 5) * 8;
            f16x8 af = *(const f16x8*)(&A[mt * 32 + (lane & 31)][kof]);
            #pragma unroll
            for (int gate = 0; gate < 4; ++gate) {
                f16x8 bfr = *(const f16x8*)(&uh[(size_t)((gate * 8 + wn) * 32 + kc) * 512 + lane * 8]);
                acc[gate] = __builtin_amdgcn_mfma_f32_32x32x16_f16(af, bfr, acc[gate], 0, 0, 0);
            }
        }
        __syncthreads();   // all MFMA A-reads done before epilogue writes A

        // ---- epilogue: gates -> c (LDS fp32), h -> A fp16 (+ out at m==4) ----
        {
            const int rb = mt * 32 + 4 * (lane >> 5);
            #pragma unroll
            for (int reg = 0; reg < 16; ++reg) {
                const int row = rb + (reg & 3) + 8 * (reg >> 2);
                const float ig = sigmoidf_(acc[0][reg] + bi);
                const float fg = sigmoidf_(acc[1][reg] + bf_);
                const float og = sigmoidf_(acc[2][reg] + bo);
                const float gg = tanh_fast(acc[3][reg] + bg);
                const float cn = fg * Cs[row][d] + ig * gg;
                Cs[row][d] = cn;
                const float hn = og * tanh_fast(cn);
                A[row][d] = (_Float16)hn;
                if (m == M_STEPS - 2)
                    out[(size_t)(s0seg + row) * 512 + d] = hn;
            }
        }
        __syncthreads();   // h visible to attention

        // ---- attention pass m+1 over fp16 x: 8 atoms per wave per iter ----
        const bool last = (m == M_STEPS - 2);
        for (int js = 0; js < SEGW; ++js) {
            const int sl = w * SEGW + js;
            const int s = lbs[sl], e = lbs[sl + 1];

            const uint4* hr = (const uint4*)(&A[sl][q * 16]);
            const uint4 H0 = hr[0], H1 = hr[1];
            const float2 h0 = h2f2(H0.x), h1 = h2f2(H0.y), h2_ = h2f2(H0.z), h3 = h2f2(H0.w);
            const float2 h4 = h2f2(H1.x), h5 = h2f2(H1.y), h6 = h2f2(H1.z), h7 = h2f2(H1.w);
            const float4 hv0 = {h0.x, h0.y, h1.x, h1.y};
            const float4 hv1 = {h2_.x, h2_.y, h3.x, h3.y};
            const float4 hv2 = {h4.x, h4.y, h5.x, h5.y};
            const float4 hv3 = {h6.x, h6.y, h7.x, h7.y};

            float a0x=0.f,a0y=0.f,a0z=0.f,a0w=0.f;
            float a1x=0.f,a1y=0.f,a1z=0.f,a1w=0.f;
            float a2x=0.f,a2y=0.f,a2z=0.f,a2w=0.f;
            float a3x=0.f,a3y=0.f,a3z=0.f,a3w=0.f;
            float ssum = 0.f;

            int i = s + g;                 // this group's first row; pair row = i+4
            uint4 A0={0,0,0,0}, B0={0,0,0,0}, A1={0,0,0,0}, B1={0,0,0,0};
            if (i < e) {
                const uint4* xr0 = (const uint4*)(&xh[(size_t)i * DIM + q * 16]);
                A0 = xr0[0]; B0 = xr0[1];
                const int r1 = (i + 4 < e) ? i + 4 : i;
                const uint4* xr1 = (const uint4*)(&xh[(size_t)r1 * DIM + q * 16]);
                A1 = xr1[0]; B1 = xr1[1];
            }
            while (i < e) {
                // 1-deep pipeline: issue next pair of row loads (clamped)
                const int inext = i + 8;
                const int il0 = (inext < e) ? inext : i;
                const int il1 = (inext + 4 < e) ? inext + 4 : i;
                const uint4* xr0 = (const uint4*)(&xh[(size_t)il0 * DIM + q * 16]);
                const uint4 n0a = xr0[0];
                const uint4 n0b = xr0[1];
                const uint4* xr1 = (const uint4*)(&xh[(size_t)il1 * DIM + q * 16]);
                const uint4 n1a = xr1[0];
                const uint4 n1b = xr1[1];

                // unpack both rows
                const float2 p0 = h2f2(A0.x), p1 = h2f2(A0.y), p2 = h2f2(A0.z), p3 = h2f2(A0.w);
                const float2 p4 = h2f2(B0.x), p5 = h2f2(B0.y), p6 = h2f2(B0.z), p7 = h2f2(B0.w);
                const float4 c0 = {p0.x, p0.y, p1.x, p1.y};
                const float4 c1 = {p2.x, p2.y, p3.x, p3.y};
                const float4 c2 = {p4.x, p4.y, p5.x, p5.y};
                const float4 c3 = {p6.x, p6.y, p7.x, p7.y};
                const float2 q0 = h2f2(A1.x), q1 = h2f2(A1.y), q2 = h2f2(A1.z), q3 = h2f2(A1.w);
                const float2 q4 = h2f2(B1.x), q5 = h2f2(B1.y), q6 = h2f2(B1.z), q7 = h2f2(B1.w);
                const float4 e0 = {q0.x, q0.y, q1.x, q1.y};
                const float4 e1 = {q2.x, q2.y, q3.x, q3.y};
                const float4 e2 = {q4.x, q4.y, q5.x, q5.y};
                const float4 e3 = {q6.x, q6.y, q7.x, q7.y};

                // two independent dot partials
                float dA = c0.x*hv0.x + c0.y*hv0.y + c0.z*hv0.z + c0.w*hv0.w
                         + c1.x*hv1.x + c1.y*hv1.y + c1.z*hv1.z + c1.w*hv1.w
                         + c2.x*hv2.x + c2.y*hv2.y + c2.z*hv2.z + c2.w*hv2.w
                         + c3.x*hv3.x + c3.y*hv3.y + c3.z*hv3.z + c3.w*hv3.w;
                float dB = e0.x*hv0.x + e0.y*hv0.y + e0.z*hv0.z + e0.w*hv0.w
                         + e1.x*hv1.x + e1.y*hv1.y + e1.z*hv1.z + e1.w*hv1.w
                         + e2.x*hv2.x + e2.y*hv2.y + e2.z*hv2.z + e2.w*hv2.w
                         + e3.x*hv3.x + e3.y*hv3.y + e3.z*hv3.z + e3.w*hv3.w;
                // interleaved butterflies (independent chains overlap latency)
                dA += __shfl_xor(dA, 1, 64);  dB += __shfl_xor(dB, 1, 64);
                dA += __shfl_xor(dA, 2, 64);  dB += __shfl_xor(dB, 2, 64);
                dA += __shfl_xor(dA, 4, 64);  dB += __shfl_xor(dB, 4, 64);
                dA += __shfl_xor(dA, 8, 64);  dB += __shfl_xor(dB, 8, 64);

                const float eeA = __expf(dA);
                const float eeB = (i + 4 < e) ? __expf(dB) : 0.0f;
                ssum += eeA + eeB;
                a0x += eeA*c0.x + eeB*e0.x; a0y += eeA*c0.y + eeB*e0.y;
                a0z += eeA*c0.z + eeB*e0.z; a0w += eeA*c0.w + eeB*e0.w;
                a1x += eeA*c1.x + eeB*e1.x; a1y += eeA*c1.y + eeB*e1.y;
                a1z += eeA*c1.z + eeB*e1.z; a1w += eeA*c1.w + eeB*e1.w;
                a2x += eeA*c2.x + eeB*e2.x; a2y += eeA*c2.y + eeB*e2.y;
                a2z += eeA*c2.z + eeB*e2.z; a2w += eeA*c2.w + eeB*e2.w;
                a3x += eeA*c3.x + eeB*e3.x; a3y += eeA*c3.y + eeB*e3.y;
                a3z += eeA*c3.z + eeB*e3.z; a3w += eeA*c3.w + eeB*e3.w;

                A0 = n0a; B0 = n0b; A1 = n1a; B1 = n1b;
                i = inext;
            }
            XRED(a0x) XRED(a0y) XRED(a0z) XRED(a0w)
            XRED(a1x) XRED(a1y) XRED(a1z) XRED(a1w)
            XRED(a2x) XRED(a2y) XRED(a2z) XRED(a2w)
            XRED(a3x) XRED(a3y) XRED(a3z) XRED(a3w)
            XRED(ssum)
            const float inv = (ssum > 0.f) ? (1.0f / ssum) : 0.f;
            float vx = (g==0) ? a0x : (g==1) ? a1x : (g==2) ? a2x : a3x;
            float vy = (g==0) ? a0y : (g==1) ? a1y : (g==2) ? a2y : a3y;
            float vz = (g==0) ? a0z : (g==1) ? a1z : (g==2) ? a2z : a3z;
            float vw = (g==0) ? a0w : (g==1) ? a1w : (g==2) ? a2w : a3w;
            if (last) {
                float4 v; v.x = vx*inv; v.y = vy*inv; v.z = vz*inv; v.w = vw*inv;
                *(float4*)(&out[(size_t)(s0seg + sl) * 512 + 256 + q * 16 + g * 4]) = v;
            } else {
                union { _Float16 h[4]; uint2 u; } R;
                R.h[0]=(_Float16)(vx*inv); R.h[1]=(_Float16)(vy*inv);
                R.h[2]=(_Float16)(vz*inv); R.h[3]=(_Float16)(vw*inv);
                *(uint2*)(&A[sl][256 + q * 16 + g * 4]) = R.u;
            }
        }
        if (m < M_STEPS - 2) __syncthreads();   // r visible to next GEMM
    }
#undef XRED
}

// ---------------------------------------------------------------------------
extern "C" void kernel_launch(void* const* d_in, const int* in_sizes, int n_in,
                              void* d_out, int out_size, void* d_ws, size_t ws_size,
                              hipStream_t stream) {
    const float* x     = (const float*)d_in[0];
    const int*   split = (const int*)d_in[1];
    const float* U     = (const float*)d_in[2];
    const float* bias  = (const float*)d_in[3];
    float* out = (float*)d_out;

    char* ws = (char*)d_ws;
    const size_t lb_bytes = ((size_t)(NB + 1) * sizeof(int) + 255) & ~(size_t)255;
    int*      lb = (int*)ws;
    _Float16* uh = (_Float16*)(ws + lb_bytes);                 // 1 MB
    _Float16* xh = (_Float16*)(ws + lb_bytes + (1 << 20));     // 256 MB

    bounds_kernel<<<(NB + 1 + 255) / 256, 256, 0, stream>>>(split, lb);
    uswz_kernel<<<1024, 256, 0, stream>>>(U, uh);

    const int smem_bytes = SEG * AST * 2 + SEG * DIM * 4 + (SEG + 1) * 4; // 132356
    set2set_fused_kernel<<<NB / SEG, NTHREADS, smem_bytes, stream>>>(
        x, lb, uh, bias, xh, out);
}

// Round 6
// 1225.665 us; speedup vs baseline: 1.0198x; 1.0198x over previous
//
#include <hip/hip_runtime.h>
#include <hip/hip_bf16.h>
#include <math.h>

#define N_ATOMS 524288
#define DIM 256
#define NB 16384          // number of molecules / segments
#define M_STEPS 6

#define SEG 64            // segments per block
#define NTHREADS 1024     // 16 waves -> 4 waves/SIMD
#define SEGW 4            // segments per wave
#define AST 520           // A row stride (fp16): 512 cols + 8 pad

typedef _Float16 f16x8 __attribute__((ext_vector_type(8)));
typedef float f32x16 __attribute__((ext_vector_type(16)));

__device__ __forceinline__ float sigmoidf_(float z) {
    return 1.0f / (1.0f + __expf(-z));
}
__device__ __forceinline__ float tanh_fast(float z) {
    return 1.0f - 2.0f / (__expf(2.0f * z) + 1.0f);
}
// unpack a uint holding two fp16
__device__ __forceinline__ float2 h2f2(unsigned u) {
    union { unsigned u; _Float16 h[2]; } x; x.u = u;
    float2 r; r.x = (float)x.h[0]; r.y = (float)x.h[1]; return r;
}

// DPP partial-sum: v += v[partner] via VALU-pipe cross-lane (no DS latency).
// CTRL: 0xB1 quad_perm[1,0,3,2] (xor1), 0x4E quad_perm[2,3,0,1] (xor2),
//       0x141 row_half_mirror (8-partner), 0x140 row_mirror (16-partner).
// Sequence of all four == xor-butterfly sum over each 16-lane group
// (bit-identical result; each stage adds a value that equals the shfl_xor one).
template <int CTRL>
__device__ __forceinline__ float dpp_radd(float v) {
    int p = __builtin_amdgcn_update_dpp(0, __float_as_int(v), CTRL, 0xF, 0xF, true);
    return v + __int_as_float(p);
}
#define DPP16SUM(v) { v = dpp_radd<0xB1>(v); v = dpp_radd<0x4E>(v); \
                      v = dpp_radd<0x141>(v); v = dpp_radd<0x140>(v); }

// ---------------------------------------------------------------------------
// Kernel 1: segment bounds via binary search (atom_split is sorted)
// ---------------------------------------------------------------------------
__global__ void bounds_kernel(const int* __restrict__ split, int* __restrict__ lb) {
    int b = blockIdx.x * blockDim.x + threadIdx.x;
    if (b > NB) return;
    int lo = 0, hi = N_ATOMS;
    while (lo < hi) {
        int mid = (lo + hi) >> 1;
        if (split[mid] < b) lo = mid + 1; else hi = mid;
    }
    lb[b] = lo;
}

// ---------------------------------------------------------------------------
// Kernel 2: pre-swizzle U (f32 [512,1024]) into fp16 B-fragment order for
// mfma_f32_32x32x16_f16. Frag f = nt*32 + kc; lane l holds
// B[k = kc*16 + (l>>5)*8 + jj][n = nt*32 + (l&31)], jj=0..7. 1 MB total.
// ---------------------------------------------------------------------------
__global__ __launch_bounds__(256) void uswz_kernel(const float* __restrict__ U,
                                                   _Float16* __restrict__ uh) {
    int d = blockIdx.x * 256 + threadIdx.x;
    int f = d >> 8;
    int r = d & 255;
    int jjp = r >> 6;
    int lane = r & 63;
    int nt = f >> 5, kc = f & 31;
    int n = nt * 32 + (lane & 31);
    int k = kc * 16 + (lane >> 5) * 8 + jjp * 2;
    union { unsigned u; _Float16 h[2]; } p;
    p.h[0] = (_Float16)U[(size_t)k * 1024 + n];
    p.h[1] = (_Float16)U[(size_t)(k + 1) * 1024 + n];
    *(unsigned*)(&uh[(size_t)(f * 64 + lane) * 8 + jjp * 2]) = p.u;
}

// ---------------------------------------------------------------------------
// Kernel 3: FULLY FUSED Set2Set, 16-wave blocks. Attention per-row reduction
// now uses DPP (VALU pipe) instead of shfl (DS pipe) to cut the per-iteration
// dependency chain from ~300 to ~60 cycles.
// ---------------------------------------------------------------------------
__global__ __launch_bounds__(NTHREADS) void set2set_fused_kernel(
    const float* __restrict__ x,       // [N_ATOMS, DIM] fp32
    const int* __restrict__ lb,        // [NB+1]
    const _Float16* __restrict__ uh,   // pre-swizzled U fp16 fragments
    const float* __restrict__ bias,    // [1024]
    _Float16* __restrict__ xh,         // [N_ATOMS, DIM] fp16 scratch
    float* __restrict__ out)           // [NB, 512]
{
    extern __shared__ char smem[];
    _Float16 (*A)[AST]  = (_Float16(*)[AST])smem;                       // 66560 B
    float    (*Cs)[DIM] = (float(*)[DIM])(smem + SEG * AST * 2);        // 65536 B
    int*     lbs        = (int*)(smem + SEG * AST * 2 + SEG * DIM * 4); // 260 B

    const int t    = threadIdx.x;
    const int w    = t >> 6;
    const int lane = t & 63;
    const int g    = lane >> 4;       // atom subgroup 0..3
    const int q    = lane & 15;       // dim subgroup 0..15
    const int s0seg = blockIdx.x * SEG;

    if (t <= SEG) lbs[t] = lb[s0seg + t];
    // zero h-half of A and c
    for (int idx = t; idx < SEG * 64; idx += NTHREADS) {
        int row = idx >> 6, j4 = idx & 63;
        uint2 z; z.x = 0u; z.y = 0u;
        *(uint2*)(&A[row][j4 * 4]) = z;                 // cols 0..255 (h) = 0
        float4 zf = {0.f, 0.f, 0.f, 0.f};
        *(float4*)(&Cs[row][j4 * 4]) = zf;
    }
    // GEMM role of this wave: row-tile mt, col-tile wn; hoist bias
    const int mt    = w >> 3;
    const int wn    = w & 7;
    const int col32 = lane & 31;
    const int d     = wn * 32 + col32;
    const float bi  = bias[d];
    const float bf_ = bias[256 + d];
    const float bo  = bias[512 + d];
    const float bg  = bias[768 + d];
    __syncthreads();

#define XRED(v) { v += __shfl_xor(v, 16, 64); v += __shfl_xor(v, 32, 64); }

    // ---------------- phase 0: mean + fp16 conversion (4 atoms/iter) --------
    for (int js = 0; js < SEGW; ++js) {
        const int sl = w * SEGW + js;
        const int s = lbs[sl], e = lbs[sl + 1];
        float a0x=0.f,a0y=0.f,a0z=0.f,a0w=0.f;
        float a1x=0.f,a1y=0.f,a1z=0.f,a1w=0.f;
        float a2x=0.f,a2y=0.f,a2z=0.f,a2w=0.f;
        float a3x=0.f,a3y=0.f,a3z=0.f,a3w=0.f;
        float cnt = 0.f;
        int i = s + g;
        float4 c0={0,0,0,0}, c1={0,0,0,0}, c2={0,0,0,0}, c3={0,0,0,0};
        if (i < e) {
            const float* xr = &x[(size_t)i * DIM + q * 16];
            c0 = *(const float4*)(xr + 0);  c1 = *(const float4*)(xr + 4);
            c2 = *(const float4*)(xr + 8);  c3 = *(const float4*)(xr + 12);
        }
        while (i < e) {
            const int inext = i + 4;
            const int iload = (inext < e) ? inext : i;
            const float* xr = &x[(size_t)iload * DIM + q * 16];
            const float4 n0 = *(const float4*)(xr + 0);
            const float4 n1 = *(const float4*)(xr + 4);
            const float4 n2 = *(const float4*)(xr + 8);
            const float4 n3 = *(const float4*)(xr + 12);

            union { _Float16 h[16]; uint4 v[2]; } P;
            P.h[0]=(_Float16)c0.x; P.h[1]=(_Float16)c0.y; P.h[2]=(_Float16)c0.z; P.h[3]=(_Float16)c0.w;
            P.h[4]=(_Float16)c1.x; P.h[5]=(_Float16)c1.y; P.h[6]=(_Float16)c1.z; P.h[7]=(_Float16)c1.w;
            P.h[8]=(_Float16)c2.x; P.h[9]=(_Float16)c2.y; P.h[10]=(_Float16)c2.z; P.h[11]=(_Float16)c2.w;
            P.h[12]=(_Float16)c3.x; P.h[13]=(_Float16)c3.y; P.h[14]=(_Float16)c3.z; P.h[15]=(_Float16)c3.w;
            uint4* xw = (uint4*)(&xh[(size_t)i * DIM + q * 16]);
            xw[0] = P.v[0]; xw[1] = P.v[1];

            cnt += 1.f;
            a0x += c0.x; a0y += c0.y; a0z += c0.z; a0w += c0.w;
            a1x += c1.x; a1y += c1.y; a1z += c1.z; a1w += c1.w;
            a2x += c2.x; a2y += c2.y; a2z += c2.z; a2w += c2.w;
            a3x += c3.x; a3y += c3.y; a3z += c3.z; a3w += c3.w;
            c0=n0; c1=n1; c2=n2; c3=n3;
            i = inext;
        }
        XRED(a0x) XRED(a0y) XRED(a0z) XRED(a0w)
        XRED(a1x) XRED(a1y) XRED(a1z) XRED(a1w)
        XRED(a2x) XRED(a2y) XRED(a2z) XRED(a2w)
        XRED(a3x) XRED(a3y) XRED(a3z) XRED(a3w)
        XRED(cnt)
        const float inv = (cnt > 0.f) ? (1.0f / cnt) : 0.f;
        float vx = (g==0) ? a0x : (g==1) ? a1x : (g==2) ? a2x : a3x;
        float vy = (g==0) ? a0y : (g==1) ? a1y : (g==2) ? a2y : a3y;
        float vz = (g==0) ? a0z : (g==1) ? a1z : (g==2) ? a2z : a3z;
        float vw = (g==0) ? a0w : (g==1) ? a1w : (g==2) ? a2w : a3w;
        union { _Float16 h[4]; uint2 u; } R;
        R.h[0]=(_Float16)(vx*inv); R.h[1]=(_Float16)(vy*inv);
        R.h[2]=(_Float16)(vz*inv); R.h[3]=(_Float16)(vw*inv);
        *(uint2*)(&A[sl][256 + q * 16 + g * 4]) = R.u;
    }
    __syncthreads();

    // ---------------- 5 x (LSTM step + attention pass) ----------------
    for (int m = 0; m < M_STEPS - 1; ++m) {
        // ---- GEMM: z = [h|r] @ U.  A fp16 in LDS; wave does 32 rows x 32 cols x 4 gates.
        f32x16 acc[4];
        #pragma unroll
        for (int et = 0; et < 4; ++et)
            #pragma unroll
            for (int qq = 0; qq < 16; ++qq) acc[et][qq] = 0.0f;

        #pragma unroll 4
        for (int kc = 0; kc < 32; ++kc) {
            const int kof = kc * 16 + (lane >> 5) * 8;
            f16x8 af = *(const f16x8*)(&A[mt * 32 + (lane & 31)][kof]);
            #pragma unroll
            for (int gate = 0; gate < 4; ++gate) {
                f16x8 bfr = *(const f16x8*)(&uh[(size_t)((gate * 8 + wn) * 32 + kc) * 512 + lane * 8]);
                acc[gate] = __builtin_amdgcn_mfma_f32_32x32x16_f16(af, bfr, acc[gate], 0, 0, 0);
            }
        }
        __syncthreads();   // all MFMA A-reads done before epilogue writes A

        // ---- epilogue: gates -> c (LDS fp32), h -> A fp16 (+ out at m==4) ----
        {
            const int rb = mt * 32 + 4 * (lane >> 5);
            #pragma unroll
            for (int reg = 0; reg < 16; ++reg) {
                const int row = rb + (reg & 3) + 8 * (reg >> 2);
                const float ig = sigmoidf_(acc[0][reg] + bi);
                const float fg = sigmoidf_(acc[1][reg] + bf_);
                const float og = sigmoidf_(acc[2][reg] + bo);
                const float gg = tanh_fast(acc[3][reg] + bg);
                const float cn = fg * Cs[row][d] + ig * gg;
                Cs[row][d] = cn;
                const float hn = og * tanh_fast(cn);
                A[row][d] = (_Float16)hn;
                if (m == M_STEPS - 2)
                    out[(size_t)(s0seg + row) * 512 + d] = hn;
            }
        }
        __syncthreads();   // h visible to attention

        // ---- attention pass m+1 over fp16 x: 8 atoms per wave per iter ----
        const bool last = (m == M_STEPS - 2);
        for (int js = 0; js < SEGW; ++js) {
            const int sl = w * SEGW + js;
            const int s = lbs[sl], e = lbs[sl + 1];

            const uint4* hr = (const uint4*)(&A[sl][q * 16]);
            const uint4 H0 = hr[0], H1 = hr[1];
            const float2 h0 = h2f2(H0.x), h1 = h2f2(H0.y), h2_ = h2f2(H0.z), h3 = h2f2(H0.w);
            const float2 h4 = h2f2(H1.x), h5 = h2f2(H1.y), h6 = h2f2(H1.z), h7 = h2f2(H1.w);
            const float4 hv0 = {h0.x, h0.y, h1.x, h1.y};
            const float4 hv1 = {h2_.x, h2_.y, h3.x, h3.y};
            const float4 hv2 = {h4.x, h4.y, h5.x, h5.y};
            const float4 hv3 = {h6.x, h6.y, h7.x, h7.y};

            float a0x=0.f,a0y=0.f,a0z=0.f,a0w=0.f;
            float a1x=0.f,a1y=0.f,a1z=0.f,a1w=0.f;
            float a2x=0.f,a2y=0.f,a2z=0.f,a2w=0.f;
            float a3x=0.f,a3y=0.f,a3z=0.f,a3w=0.f;
            float ssum = 0.f;

            int i = s + g;                 // this group's first row; pair row = i+4
            uint4 A0={0,0,0,0}, B0={0,0,0,0}, A1={0,0,0,0}, B1={0,0,0,0};
            if (i < e) {
                const uint4* xr0 = (const uint4*)(&xh[(size_t)i * DIM + q * 16]);
                A0 = xr0[0]; B0 = xr0[1];
                const int r1 = (i + 4 < e) ? i + 4 : i;
                const uint4* xr1 = (const uint4*)(&xh[(size_t)r1 * DIM + q * 16]);
                A1 = xr1[0]; B1 = xr1[1];
            }
            while (i < e) {
                // 1-deep pipeline: issue next pair of row loads (clamped)
                const int inext = i + 8;
                const int il0 = (inext < e) ? inext : i;
                const int il1 = (inext + 4 < e) ? inext + 4 : i;
                const uint4* xr0 = (const uint4*)(&xh[(size_t)il0 * DIM + q * 16]);
                const uint4 n0a = xr0[0];
                const uint4 n0b = xr0[1];
                const uint4* xr1 = (const uint4*)(&xh[(size_t)il1 * DIM + q * 16]);
                const uint4 n1a = xr1[0];
                const uint4 n1b = xr1[1];

                // unpack both rows
                const float2 p0 = h2f2(A0.x), p1 = h2f2(A0.y), p2 = h2f2(A0.z), p3 = h2f2(A0.w);
                const float2 p4 = h2f2(B0.x), p5 = h2f2(B0.y), p6 = h2f2(B0.z), p7 = h2f2(B0.w);
                const float4 c0 = {p0.x, p0.y, p1.x, p1.y};
                const float4 c1 = {p2.x, p2.y, p3.x, p3.y};
                const float4 c2 = {p4.x, p4.y, p5.x, p5.y};
                const float4 c3 = {p6.x, p6.y, p7.x, p7.y};
                const float2 q0 = h2f2(A1.x), q1 = h2f2(A1.y), q2 = h2f2(A1.z), q3 = h2f2(A1.w);
                const float2 q4 = h2f2(B1.x), q5 = h2f2(B1.y), q6 = h2f2(B1.z), q7 = h2f2(B1.w);
                const float4 e0 = {q0.x, q0.y, q1.x, q1.y};
                const float4 e1 = {q2.x, q2.y, q3.x, q3.y};
                const float4 e2 = {q4.x, q4.y, q5.x, q5.y};
                const float4 e3 = {q6.x, q6.y, q7.x, q7.y};

                // two independent dot partials
                float dA = c0.x*hv0.x + c0.y*hv0.y + c0.z*hv0.z + c0.w*hv0.w
                         + c1.x*hv1.x + c1.y*hv1.y + c1.z*hv1.z + c1.w*hv1.w
                         + c2.x*hv2.x + c2.y*hv2.y + c2.z*hv2.z + c2.w*hv2.w
                         + c3.x*hv3.x + c3.y*hv3.y + c3.z*hv3.z + c3.w*hv3.w;
                float dB = e0.x*hv0.x + e0.y*hv0.y + e0.z*hv0.z + e0.w*hv0.w
                         + e1.x*hv1.x + e1.y*hv1.y + e1.z*hv1.z + e1.w*hv1.w
                         + e2.x*hv2.x + e2.y*hv2.y + e2.z*hv2.z + e2.w*hv2.w
                         + e3.x*hv3.x + e3.y*hv3.y + e3.z*hv3.z + e3.w*hv3.w;
                // DPP 16-lane sums on the VALU pipe (was: 4x shfl_xor via DS)
                DPP16SUM(dA)
                DPP16SUM(dB)

                const float eeA = __expf(dA);
                const float eeB = (i + 4 < e) ? __expf(dB) : 0.0f;
                ssum += eeA + eeB;
                a0x += eeA*c0.x + eeB*e0.x; a0y += eeA*c0.y + eeB*e0.y;
                a0z += eeA*c0.z + eeB*e0.z; a0w += eeA*c0.w + eeB*e0.w;
                a1x += eeA*c1.x + eeB*e1.x; a1y += eeA*c1.y + eeB*e1.y;
                a1z += eeA*c1.z + eeB*e1.z; a1w += eeA*c1.w + eeB*e1.w;
                a2x += eeA*c2.x + eeB*e2.x; a2y += eeA*c2.y + eeB*e2.y;
                a2z += eeA*c2.z + eeB*e2.z; a2w += eeA*c2.w + eeB*e2.w;
                a3x += eeA*c3.x + eeB*e3.x; a3y += eeA*c3.y + eeB*e3.y;
                a3z += eeA*c3.z + eeB*e3.z; a3w += eeA*c3.w + eeB*e3.w;

                A0 = n0a; B0 = n0b; A1 = n1a; B1 = n1b;
                i = inext;
            }
            XRED(a0x) XRED(a0y) XRED(a0z) XRED(a0w)
            XRED(a1x) XRED(a1y) XRED(a1z) XRED(a1w)
            XRED(a2x) XRED(a2y) XRED(a2z) XRED(a2w)
            XRED(a3x) XRED(a3y) XRED(a3z) XRED(a3w)
            XRED(ssum)
            const float inv = (ssum > 0.f) ? (1.0f / ssum) : 0.f;
            float vx = (g==0) ? a0x : (g==1) ? a1x : (g==2) ? a2x : a3x;
            float vy = (g==0) ? a0y : (g==1) ? a1y : (g==2) ? a2y : a3y;
            float vz = (g==0) ? a0z : (g==1) ? a1z : (g==2) ? a2z : a3z;
            float vw = (g==0) ? a0w : (g==1) ? a1w : (g==2) ? a2w : a3w;
            if (last) {
                float4 v; v.x = vx*inv; v.y = vy*inv; v.z = vz*inv; v.w = vw*inv;
                *(float4*)(&out[(size_t)(s0seg + sl) * 512 + 256 + q * 16 + g * 4]) = v;
            } else {
                union { _Float16 h[4]; uint2 u; } R;
                R.h[0]=(_Float16)(vx*inv); R.h[1]=(_Float16)(vy*inv);
                R.h[2]=(_Float16)(vz*inv); R.h[3]=(_Float16)(vw*inv);
                *(uint2*)(&A[sl][256 + q * 16 + g * 4]) = R.u;
            }
        }
        if (m < M_STEPS - 2) __syncthreads();   // r visible to next GEMM
    }
#undef XRED
}

// ---------------------------------------------------------------------------
extern "C" void kernel_launch(void* const* d_in, const int* in_sizes, int n_in,
                              void* d_out, int out_size, void* d_ws, size_t ws_size,
                              hipStream_t stream) {
    const float* x     = (const float*)d_in[0];
    const int*   split = (const int*)d_in[1];
    const float* U     = (const float*)d_in[2];
    const float* bias  = (const float*)d_in[3];
    float* out = (float*)d_out;

    char* ws = (char*)d_ws;
    const size_t lb_bytes = ((size_t)(NB + 1) * sizeof(int) + 255) & ~(size_t)255;
    int*      lb = (int*)ws;
    _Float16* uh = (_Float16*)(ws + lb_bytes);                 // 1 MB
    _Float16* xh = (_Float16*)(ws + lb_bytes + (1 << 20));     // 256 MB

    bounds_kernel<<<(NB + 1 + 255) / 256, 256, 0, stream>>>(split, lb);
    uswz_kernel<<<1024, 256, 0, stream>>>(U, uh);

    const int smem_bytes = SEG * AST * 2 + SEG * DIM * 4 + (SEG + 1) * 4; // 132356
    set2set_fused_kernel<<<NB / SEG, NTHREADS, smem_bytes, stream>>>(
        x, lb, uh, bias, xh, out);
}